// Round 10
// baseline (138.597 us; speedup 1.0000x reference)
//
#include <hip/hip_runtime.h>
#include <hip/hip_bf16.h>

// Problem constants: B=4, C=64, O=64, H=W=128, K=3, PAD=1
#define BB 4
#define CC 64
#define OO 64
#define HH 128
#define WW 128
#define HW (HH * WW)       // 16384
#define K2 9
#define OCOFF 18           // 2*K2 offset channels
#define STRD 20            // u32 per px row in LDS (16 data + 4 pad)

typedef __attribute__((ext_vector_type(8))) short short8;     // 8 bf16 = 4 VGPR
typedef __attribute__((ext_vector_type(16))) float f32x16;    // MFMA 32x32 acc

union U8 { unsigned u[4]; short8 s8; };

__device__ __forceinline__ float uf(unsigned u) { return __builtin_bit_cast(float, u); }

// packed f32->bf16 via HW cvt: dst[15:0]=bf16(a), dst[31:16]=bf16(b)
__device__ __forceinline__ unsigned cvtpk(float a, float b) {
  unsigned r;
  asm("v_cvt_pk_bf16_f32 %0, %1, %2" : "=v"(r) : "v"(a), "v"(b));
  return r;
}
// hi/lo split of a value pair
__device__ __forceinline__ void split2(float a, float b, unsigned& ph, unsigned& pl) {
  ph = cvtpk(a, b);
  float ra = a - uf(ph << 16);
  float rb = b - uf(ph & 0xFFFF0000u);
  pl = cvtpk(ra, rb);
}

// RNE float->bf16 bit-twiddle (prep kernel only; validated r4-r9)
__device__ __forceinline__ unsigned short bf16_rne(float v) {
  unsigned u = __builtin_bit_cast(unsigned, v);
  return (unsigned short)((u + 0x7FFFu + ((u >> 16) & 1u)) >> 16);
}
__device__ __forceinline__ void bf16_split(float v, unsigned short& hi, unsigned short& lo) {
  hi = bf16_rne(v);
  float hf = __builtin_bit_cast(float, (unsigned)hi << 16);
  lo = bf16_rne(v - hf);
}
__device__ __forceinline__ float4 ld4(const float* p) { return *(const float4*)p; }

// ---------------------------------------------------------------------------
// prep_all: one kernel, three block-ranges (all validated r4-r9). UNCHANGED.
// ---------------------------------------------------------------------------
__global__ __launch_bounds__(256) void prep_all(
    const float* __restrict__ x, const float* __restrict__ weight,
    const float* __restrict__ w_off, float* __restrict__ xt,
    unsigned* __restrict__ wf, unsigned* __restrict__ wof) {
  int blk = blockIdx.x;
  int t = threadIdx.x;
  if (blk < 2048) {
    __shared__ float tile[64][33];
    int wt = blk & 3, h = (blk >> 2) & 127, b = blk >> 9;
    int w0 = wt * 32;
    {
      int w_l = t & 31, c_l = t >> 5;
#pragma unroll
      for (int i = 0; i < 8; ++i) {
        int cc = c_l * 8 + i;
        tile[cc][w_l] = x[(((size_t)b * 64 + cc) * 128 + h) * 128 + w0 + w_l];
      }
    }
    __syncthreads();
    {
      int c_w = t & 63, w_w = t >> 6;
#pragma unroll
      for (int i = 0; i < 8; ++i) {
        int wl = w_w * 8 + i;
        xt[(((size_t)b * 128 + h) * 128 + w0 + wl) * 64 + c_w] = tile[c_w][wl];
      }
    }
    return;
  }
  if (blk < 2048 + 144) {
    int d = (blk - 2048) * 256 + t;
    if (d >= 9 * 4096) return;
    int j2 = d & 3, l = (d >> 2) & 63, hh = (d >> 8) & 1, s = (d >> 9) & 3,
        m = (d >> 11) & 1, c = d >> 12;
    int o = m * 32 + (l & 31);
    int g = l >> 5;
    int ch0 = s * 16 + g * 8 + j2 * 2;
    float v0 = weight[(o * 64 + ch0) * 9 + c];
    float v1 = weight[(o * 64 + ch0 + 1) * 9 + c];
    unsigned short h0, l0, h1, l1;
    bf16_split(v0, h0, l0);
    bf16_split(v1, h1, l1);
    unsigned short b0 = hh ? l0 : h0;
    unsigned short b1 = hh ? l1 : h1;
    wf[d] = (unsigned)b0 | ((unsigned)b1 << 16);
    return;
  }
  {
    int d = (blk - 2192) * 256 + t;
    if (d >= 9 * 2048) return;
    int j2 = d & 3, l = (d >> 2) & 63, hh = (d >> 8) & 1, s = (d >> 9) & 3,
        c = d >> 11;
    int oc = l & 31;
    int g = l >> 5;
    int ch0 = s * 16 + g * 8 + j2 * 2;
    unsigned r = 0;
    if (oc < OCOFF) {
      float v0 = w_off[(oc * 64 + ch0) * 9 + c];
      float v1 = w_off[(oc * 64 + ch0 + 1) * 9 + c];
      unsigned short h0, l0, h1, l1;
      bf16_split(v0, h0, l0);
      bf16_split(v1, h1, l1);
      unsigned short b0 = hh ? l0 : h0;
      unsigned short b1 = hh ? l1 : h1;
      r = (unsigned)b0 | ((unsigned)b1 << 16);
    }
    wof[d] = r;
    return;
  }
}

// ---------------------------------------------------------------------------
// tap descriptor (validated r4-r9)
// ---------------------------------------------------------------------------
struct TapD { int o00, o01, o10, o11; float w00, w01, w10, w11; };
struct TapW { float w00, w01, w10, w11; };

__device__ __forceinline__ TapD mk_tapd(float oyv, float oxv, int h, int wpix, int kk) {
  TapD t;
  const int dy = kk / 3 - 1, dx = kk - (kk / 3) * 3 - 1;
  float py = oyv + (float)(h + dy);
  float px = oxv + (float)(wpix + dx);
  float y0f = floorf(py), x0f = floorf(px);
  float wy1 = py - y0f, wx1 = px - x0f;
  float wy0 = 1.0f - wy1, wx0 = 1.0f - wx1;
  int y0 = (int)y0f, x0 = (int)x0f, y1 = y0 + 1, x1 = x0 + 1;
  bool vy0 = (unsigned)y0 < (unsigned)HH, vy1 = (unsigned)y1 < (unsigned)HH;
  bool vx0 = (unsigned)x0 < (unsigned)WW, vx1 = (unsigned)x1 < (unsigned)WW;
  t.w00 = (vy0 && vx0) ? wy0 * wx0 : 0.0f;
  t.w01 = (vy0 && vx1) ? wy0 * wx1 : 0.0f;
  t.w10 = (vy1 && vx0) ? wy1 * wx0 : 0.0f;
  t.w11 = (vy1 && vx1) ? wy1 * wx1 : 0.0f;
  int y0c = min(max(y0, 0), HH - 1), y1c = min(max(y1, 0), HH - 1);
  int x0c = min(max(x0, 0), WW - 1), x1c = min(max(x1, 0), WW - 1);
  t.o00 = (y0c * WW + x0c) * CC;
  t.o01 = (y0c * WW + x1c) * CC;
  t.o10 = (y1c * WW + x0c) * CC;
  t.o11 = (y1c * WW + x1c) * CC;
  return t;
}

// ---------------------------------------------------------------------------
// PHASE 1 pieces (K-split: wave covers ksteps {2sh, 2sh+1} = ch 32sh..32sh+31)
// lane: px = wbase+P, granule g (8ch within the half).
// ---------------------------------------------------------------------------
__device__ __forceinline__ unsigned stageO1K(uint4 (&T)[4], const float* xb,
                                             int h, int wP, int chb, int g, int c) {
  const int dy = c / 3 - 1, dx = c - (c / 3) * 3 - 1;
  const int y = h + dy, xp = wP + dx;
  bool valid = ((unsigned)y < (unsigned)HH) && ((unsigned)xp < (unsigned)WW);
  int yc = min(max(y, 0), HH - 1), xc = min(max(xp, 0), WW - 1);
  const uint4* rowp = (const uint4*)(xb + (size_t)(yc * WW + xc) * CC);
#pragma unroll
  for (int si = 0; si < 2; ++si) {
    int u4i = (chb + si * 16 + g * 8) >> 2;
    T[2 * si]     = rowp[u4i];
    T[2 * si + 1] = rowp[u4i + 1];
  }
  return valid ? 0xFFFFFFFFu : 0u;
}

__device__ __forceinline__ void p1_tapK(f32x16& accO, uint4 (&TC)[4], unsigned mskC,
                                        uint4 (&TN)[4], unsigned& mskN,
                                        const float* xb, const unsigned* wofrag,
                                        int h, int wP, int chb, int g, int l,
                                        int sh, int c, bool last) {
  if (!last) {
    mskN = stageO1K(TN, xb, h, wP, chb, g, c + 1);
    __builtin_amdgcn_sched_barrier(0);
  }
#pragma unroll
  for (int si = 0; si < 2; ++si) {
    uint4 u0 = TC[2 * si], u1 = TC[2 * si + 1];
    u0.x &= mskC; u0.y &= mskC; u0.z &= mskC; u0.w &= mskC;
    u1.x &= mskC; u1.y &= mskC; u1.z &= mskC; u1.w &= mskC;
    U8 sv, lv;
    split2(uf(u0.x), uf(u0.y), sv.u[0], lv.u[0]);
    split2(uf(u0.z), uf(u0.w), sv.u[1], lv.u[1]);
    split2(uf(u1.x), uf(u1.y), sv.u[2], lv.u[2]);
    split2(uf(u1.z), uf(u1.w), sv.u[3], lv.u[3]);
    const int s = sh * 2 + si;
    const unsigned* wb = wofrag + ((size_t)((c * 8 + s * 2) * 64 + l)) * 4;
    short8 wh = *(const short8*)(wb);
    short8 wl = *(const short8*)(wb + 256);
    __builtin_amdgcn_s_setprio(1);
    accO = __builtin_amdgcn_mfma_f32_32x32x16_bf16(wh, sv.s8, accO, 0, 0, 0);
    accO = __builtin_amdgcn_mfma_f32_32x32x16_bf16(wh, lv.s8, accO, 0, 0, 0);
    accO = __builtin_amdgcn_mfma_f32_32x32x16_bf16(wl, sv.s8, accO, 0, 0, 0);
    __builtin_amdgcn_s_setprio(0);
  }
}

// ---------------------------------------------------------------------------
// PHASE 2 pieces. Lane map: j = l&7 (4-ch granule within the wave's 32-ch
// half), pq = l>>3 (px within a round of 8). Each ld4 = one full 128B line.
// ---------------------------------------------------------------------------
__device__ __forceinline__ TapW stageD2K(float4 (&st)[4], const float* xb,
                                         const float* ol, int h, int wbase,
                                         int pgl0, int pq, int chj, int r, int c) {
  float2 o = *(const float2*)&ol[(pgl0 + r * 8 + pq) * OCOFF + 2 * c];
  TapD t = mk_tapd(o.x, o.y, h, wbase + r * 8 + pq, c);
  st[0] = ld4(xb + t.o00 + chj);  st[1] = ld4(xb + t.o01 + chj);
  st[2] = ld4(xb + t.o10 + chj);  st[3] = ld4(xb + t.o11 + chj);
  TapW w = { t.w00, t.w01, t.w10, t.w11 };
  return w;
}

__device__ __forceinline__ void consDK(unsigned* mh, unsigned* ml, int pl, int j,
                                       const float4 (&st)[4], const TapW& t) {
  float v[4];
#pragma unroll
  for (int q = 0; q < 4; ++q)
    v[q] = fmaf(t.w00, st[0][q], fmaf(t.w01, st[1][q],
           fmaf(t.w10, st[2][q], t.w11 * st[3][q])));
  unsigned h01, l01, h23, l23;
  split2(v[0], v[1], h01, l01);
  split2(v[2], v[3], h23, l23);
  int idx = pl * STRD + j * 2;
  *(uint2*)&mh[idx] = make_uint2(h01, h23);
  *(uint2*)&ml[idx] = make_uint2(l01, l23);
}

__device__ __forceinline__ void p2_mfmaK(f32x16& acc0, f32x16& acc1,
                                         const unsigned* mh, const unsigned* ml,
                                         const unsigned* wfrag,
                                         int P, int g, int l, int sh, int c) {
  __builtin_amdgcn_s_setprio(1);
#pragma unroll
  for (int si = 0; si < 2; ++si) {
    int ridx = P * STRD + si * 8 + g * 4;
    short8 sh8 = *(const short8*)&mh[ridx];
    short8 sl8 = *(const short8*)&ml[ridx];
    const int s = sh * 2 + si;
    const unsigned* wb = wfrag + ((size_t)((c * 16 + s * 2) * 64 + l)) * 4;
    short8 wh0 = *(const short8*)(wb);
    short8 wl0 = *(const short8*)(wb + 256);
    short8 wh1 = *(const short8*)(wb + 2048);
    short8 wl1 = *(const short8*)(wb + 2304);
    acc0 = __builtin_amdgcn_mfma_f32_32x32x16_bf16(wh0, sh8, acc0, 0, 0, 0);
    acc0 = __builtin_amdgcn_mfma_f32_32x32x16_bf16(wh0, sl8, acc0, 0, 0, 0);
    acc0 = __builtin_amdgcn_mfma_f32_32x32x16_bf16(wl0, sh8, acc0, 0, 0, 0);
    acc1 = __builtin_amdgcn_mfma_f32_32x32x16_bf16(wh1, sh8, acc1, 0, 0, 0);
    acc1 = __builtin_amdgcn_mfma_f32_32x32x16_bf16(wh1, sl8, acc1, 0, 0, 0);
    acc1 = __builtin_amdgcn_mfma_f32_32x32x16_bf16(wl1, sh8, acc1, 0, 0, 0);
  }
  __builtin_amdgcn_s_setprio(0);
}

// 3-buffer rotation: entering a tap, SA=(c,r0), SB=(c,r1), SC free.
__device__ __forceinline__ void p2_tapK(f32x16& acc0, f32x16& acc1,
    float4 (&SA)[4], float4 (&SB)[4], float4 (&SC)[4],
    TapW& tA, TapW& tB, TapW& tC,
    unsigned* mh, unsigned* ml, const float* xb, const float* ol,
    const unsigned* wfrag, int h, int wbase, int pgl0, int pq, int j, int chj,
    int P, int g, int l, int sh, int c, bool last) {
  tC = stageD2K(SC, xb, ol, h, wbase, pgl0, pq, chj, 2, c);
  __builtin_amdgcn_sched_barrier(0);
  consDK(mh, ml, 0 * 8 + pq, j, SA, tA);
  tA = stageD2K(SA, xb, ol, h, wbase, pgl0, pq, chj, 3, c);
  __builtin_amdgcn_sched_barrier(0);
  consDK(mh, ml, 1 * 8 + pq, j, SB, tB);
  if (!last) {
    tB = stageD2K(SB, xb, ol, h, wbase, pgl0, pq, chj, 0, c + 1);
    __builtin_amdgcn_sched_barrier(0);
  }
  consDK(mh, ml, 2 * 8 + pq, j, SC, tC);
  if (!last) {
    tC = stageD2K(SC, xb, ol, h, wbase, pgl0, pq, chj, 1, c + 1);
    __builtin_amdgcn_sched_barrier(0);
  }
  consDK(mh, ml, 3 * 8 + pq, j, SA, tA);
  p2_mfmaK(acc0, acc1, mh, ml, wfrag, P, g, l, sh, c);
  // exit: SB=(c+1,r0), SC=(c+1,r1), SA free -> caller rotates (SA,SB,SC)->(SB,SC,SA)
}

// ---------------------------------------------------------------------------
// fused kernel, K-SPLIT: block = 256 thr = 4 waves = 2 px-groups x 2 khalves.
// Wave (pg, sh): 32 px (pg), ch 32sh..32sh+31. 4 waves/SIMD at grid 1024.
// Partial accs reduced via lred LDS (2 barriers phase-1, 3 barriers epilogue).
// ---------------------------------------------------------------------------
__global__ __launch_bounds__(256, 4) void fused_deform(
    const float* __restrict__ xt, const unsigned* __restrict__ wfrag,
    const unsigned* __restrict__ wofrag, const float* __restrict__ b_off,
    const float* __restrict__ bias, float* __restrict__ out) {
  __shared__ __align__(16) unsigned smph[4][32 * STRD];   // 10.2 KB
  __shared__ __align__(16) unsigned smpl[4][32 * STRD];   // 10.2 KB
  __shared__ __align__(16) float ol[64 * OCOFF];          // 4.6 KB
  __shared__ __align__(16) float lred[2][64][17];         // 8.7 KB

  const int blk = blockIdx.x;
  const int sx = (blk & 7) * 128 + (blk >> 3);   // bijective: 1024 % 8 == 0
  const int seg = sx & 1, h = (sx >> 1) & 127, b = sx >> 8;
  const int tid = threadIdx.x;
  const int l = tid & 63, wv = tid >> 6;
  const int pg = wv & 1, sh = wv >> 1;
  const int P = l & 31, g = l >> 5;
  const int j = l & 7, pq = l >> 3;
  const int wbase = seg * 64 + pg * 32;          // w coord of wave's px 0
  const int pgl0 = pg * 32;                      // block-local px base
  const int chb = sh * 32;                       // wave's channel-half base
  const int chj = chb + j * 4;                   // lane's gather ch base

  const float* xb = xt + (size_t)b * HW * CC;
  unsigned* mh = smph[wv];
  unsigned* ml = smpl[wv];

  // ======================= PHASE 1: offset conv (K-split) ==============
  {
    f32x16 accO = {0,0,0,0,0,0,0,0,0,0,0,0,0,0,0,0};
    const int wP = wbase + P;
    uint4 TA[4], TB[4];
    unsigned mskA = 0, mskB = 0;
    mskA = stageO1K(TA, xb, h, wP, chb, g, 0);
    __builtin_amdgcn_sched_barrier(0);
    p1_tapK(accO, TA, mskA, TB, mskB, xb, wofrag, h, wP, chb, g, l, sh, 0, false);
    p1_tapK(accO, TB, mskB, TA, mskA, xb, wofrag, h, wP, chb, g, l, sh, 1, false);
    p1_tapK(accO, TA, mskA, TB, mskB, xb, wofrag, h, wP, chb, g, l, sh, 2, false);
    p1_tapK(accO, TB, mskB, TA, mskA, xb, wofrag, h, wP, chb, g, l, sh, 3, false);
    p1_tapK(accO, TA, mskA, TB, mskB, xb, wofrag, h, wP, chb, g, l, sh, 4, false);
    p1_tapK(accO, TB, mskB, TA, mskA, xb, wofrag, h, wP, chb, g, l, sh, 5, false);
    p1_tapK(accO, TA, mskA, TB, mskB, xb, wofrag, h, wP, chb, g, l, sh, 6, false);
    p1_tapK(accO, TB, mskB, TA, mskA, xb, wofrag, h, wP, chb, g, l, sh, 7, false);
    p1_tapK(accO, TA, mskA, TB, mskB, xb, wofrag, h, wP, chb, g, l, sh, 8, true);
    // cross-sh reduce -> ol  (D layout col=P, row=(r&3)+8*(r>>2)+4g, validated)
    if (sh == 1) {
#pragma unroll
      for (int r = 0; r < 16; ++r) lred[pg][l][r] = accO[r];
    }
    __syncthreads();
    if (sh == 0) {
#pragma unroll
      for (int r = 0; r < 16; ++r) {
        int oc = (r & 3) + 8 * (r >> 2) + 4 * g;
        if (oc < OCOFF)
          ol[(pgl0 + P) * OCOFF + oc] = accO[r] + lred[pg][l][r] + b_off[oc];
      }
    }
    __syncthreads();
  }

  // ======================= PHASE 2: deformable conv (K-split) ==========
  f32x16 acc0 = {0,0,0,0,0,0,0,0,0,0,0,0,0,0,0,0};
  f32x16 acc1 = {0,0,0,0,0,0,0,0,0,0,0,0,0,0,0,0};
  {
    float4 S0[4], S1[4], S2[4];
    TapW t0, t1, t2;
    t0 = stageD2K(S0, xb, ol, h, wbase, pgl0, pq, chj, 0, 0);
    __builtin_amdgcn_sched_barrier(0);
    t1 = stageD2K(S1, xb, ol, h, wbase, pgl0, pq, chj, 1, 0);
    __builtin_amdgcn_sched_barrier(0);
    p2_tapK(acc0, acc1, S0, S1, S2, t0, t1, t2, mh, ml, xb, ol, wfrag,
            h, wbase, pgl0, pq, j, chj, P, g, l, sh, 0, false);
    p2_tapK(acc0, acc1, S1, S2, S0, t1, t2, t0, mh, ml, xb, ol, wfrag,
            h, wbase, pgl0, pq, j, chj, P, g, l, sh, 1, false);
    p2_tapK(acc0, acc1, S2, S0, S1, t2, t0, t1, mh, ml, xb, ol, wfrag,
            h, wbase, pgl0, pq, j, chj, P, g, l, sh, 2, false);
    p2_tapK(acc0, acc1, S0, S1, S2, t0, t1, t2, mh, ml, xb, ol, wfrag,
            h, wbase, pgl0, pq, j, chj, P, g, l, sh, 3, false);
    p2_tapK(acc0, acc1, S1, S2, S0, t1, t2, t0, mh, ml, xb, ol, wfrag,
            h, wbase, pgl0, pq, j, chj, P, g, l, sh, 4, false);
    p2_tapK(acc0, acc1, S2, S0, S1, t2, t0, t1, mh, ml, xb, ol, wfrag,
            h, wbase, pgl0, pq, j, chj, P, g, l, sh, 5, false);
    p2_tapK(acc0, acc1, S0, S1, S2, t0, t1, t2, mh, ml, xb, ol, wfrag,
            h, wbase, pgl0, pq, j, chj, P, g, l, sh, 6, false);
    p2_tapK(acc0, acc1, S1, S2, S0, t1, t2, t0, mh, ml, xb, ol, wfrag,
            h, wbase, pgl0, pq, j, chj, P, g, l, sh, 7, false);
    p2_tapK(acc0, acc1, S2, S0, S1, t2, t0, t1, mh, ml, xb, ol, wfrag,
            h, wbase, pgl0, pq, j, chj, P, g, l, sh, 8, true);
  }

  // ============ epilogue: cross-sh reduce (two passes) + store ==========
  const int wpix = wbase + P;
  if (sh == 1) {
#pragma unroll
    for (int r = 0; r < 16; ++r) lred[pg][l][r] = acc0[r];
  }
  __syncthreads();
  if (sh == 0) {
#pragma unroll
    for (int r = 0; r < 16; ++r) {
      int o0 = (r & 3) + 8 * (r >> 2) + 4 * g;
      out[(((size_t)b * 64 + o0) * 128 + h) * 128 + wpix] =
          acc0[r] + lred[pg][l][r] + bias[o0];
    }
  }
  __syncthreads();
  if (sh == 1) {
#pragma unroll
    for (int r = 0; r < 16; ++r) lred[pg][l][r] = acc1[r];
  }
  __syncthreads();
  if (sh == 0) {
#pragma unroll
    for (int r = 0; r < 16; ++r) {
      int o0 = (r & 3) + 8 * (r >> 2) + 4 * g;
      out[(((size_t)b * 64 + 32 + o0) * 128 + h) * 128 + wpix] =
          acc1[r] + lred[pg][l][r] + bias[32 + o0];
    }
  }
}

// ---------------------------------------------------------------------------
extern "C" void kernel_launch(void* const* d_in, const int* in_sizes, int n_in,
                              void* d_out, int out_size, void* d_ws, size_t ws_size,
                              hipStream_t stream) {
  const float* x      = (const float*)d_in[0];
  const float* w_off  = (const float*)d_in[1];
  const float* b_off  = (const float*)d_in[2];
  const float* weight = (const float*)d_in[3];
  const float* bias   = (const float*)d_in[4];
  float* out = (float*)d_out;

  // workspace: xt | wfrag | wofrag  (~17 MB, proven)
  float*    xt     = (float*)d_ws;                       // 4,194,304 f
  unsigned* wfrag  = (unsigned*)(xt + (size_t)4194304);  // 36,864 dw
  unsigned* wofrag = wfrag + 36864;                      // 18,432 dw

  prep_all<<<2264, 256, 0, stream>>>(x, weight, w_off, xt, wfrag, wofrag);
  fused_deform<<<1024, 256, 0, stream>>>(xt, wfrag, wofrag, b_off, bias, out);
}